// Round 9
// baseline (875.266 us; speedup 1.0000x reference)
//
#include <hip/hip_runtime.h>

#define NE   15000   // edges
#define NVX  8000    // nodes
#define EPAD 15104   // 118*128 padded edge count
#define NT_E 118     // edge tiles of 128

typedef __attribute__((ext_vector_type(8))) short short8;   // 8 x bf16 (4 VGPRs)
typedef __attribute__((ext_vector_type(4))) float f32x4;

static __device__ __forceinline__ unsigned short f2b(float f){
  unsigned int u = __float_as_uint(f);
  u += 0x7fffu + ((u >> 16) & 1u);          // RNE
  return (unsigned short)(u >> 16);
}

// ---------------- P0: f32 -> bf16 bulk convert ----------------
__global__ __launch_bounds__(256) void k_cvt(const float* __restrict__ in,
                                             unsigned short* __restrict__ out, int n){
  int i = (blockIdx.x * 256 + threadIdx.x) * 4;
  if (i >= n) return;
  float4 v = *(const float4*)(in + i);
  ushort4 o;
  o.x = f2b(v.x); o.y = f2b(v.y); o.z = f2b(v.z); o.w = f2b(v.w);
  *(ushort4*)(out + i) = o;
}

// ---------------- P_h1: h1T[h][e] = relu(ea @ W1 + b1), transposed, zero-padded ----
__global__ __launch_bounds__(256) void k_h1(const float* __restrict__ ea,
                                            const float* __restrict__ W1,
                                            const float* __restrict__ b1,
                                            float* __restrict__ h1T){
  __shared__ float sW1[16*128];
  __shared__ float sb1[128];
  int t = threadIdx.x;
  #pragma unroll
  for (int i = 0; i < 8; ++i) sW1[i*256 + t] = W1[i*256 + t];
  if (t < 128) sb1[t] = b1[t];
  __syncthreads();
  int e = blockIdx.x * 64 + (t & 63);
  int hg = t >> 6;                    // wave id -> 32-h group
  bool valid = e < NE;
  int esafe = valid ? e : 0;
  float a[16];
  #pragma unroll
  for (int i = 0; i < 4; ++i){
    float4 v = *(const float4*)(ea + (size_t)esafe*16 + i*4);
    a[i*4+0]=v.x; a[i*4+1]=v.y; a[i*4+2]=v.z; a[i*4+3]=v.w;
  }
  for (int hh = 0; hh < 32; ++hh){
    int h = hg*32 + hh;
    float s = sb1[h];
    #pragma unroll
    for (int k = 0; k < 16; ++k) s = fmaf(a[k], sW1[k*128 + h], s);
    s = fmaxf(s, 0.f);
    h1T[(size_t)h*EPAD + e] = valid ? s : 0.f;   // coalesced along e
  }
}

// ---------------- P1: transpose + bf16 + XOR-swizzle weight blocks ----------------
// Each block b produces a 32KB block T[o][k] (bf16) with byte^((o&7)<<4) swizzle baked in.
// b in [0,127]: W2 block h ; b==128: b2 (a 128x128 matrix) ; b==129..132: W0,root,WmA,WmB.
// k_big stages these blocks BYTE-LINEARLY into LDS via global_load_lds, so the baked-in
// swizzle carries over; ds_read uses the same XOR.
__global__ __launch_bounds__(256) void k_wt(const float* __restrict__ W2,
                                            const float* __restrict__ b2,
                                            const float* __restrict__ W0,
                                            const float* __restrict__ root,
                                            const float* __restrict__ Wm,
                                            unsigned short* __restrict__ W2T,
                                            unsigned short* __restrict__ sWt){
  int b = blockIdx.x;
  const float* src;
  unsigned short* out;
  if (b < 128)      { src = W2 + (size_t)b*16384; out = W2T + (size_t)b*16384; }
  else if (b == 128){ src = b2;                   out = W2T + (size_t)128*16384; }
  else {
    int s = b - 129;
    out = sWt + (size_t)s*16384;
    src = (s==0) ? W0 : (s==1) ? root : (s==2) ? Wm : (Wm + 128*128);
  }
  int t = threadIdx.x;
  int o = t & 127, half = t >> 7;
  for (int it = 0; it < 8; ++it){
    int d0 = half*64 + it*8;
    unsigned int pk[4];
    #pragma unroll
    for (int j = 0; j < 4; ++j){
      float v0 = src[(size_t)(d0 + 2*j    )*128 + o];   // coalesced across lanes (consecutive o)
      float v1 = src[(size_t)(d0 + 2*j + 1)*128 + o];
      pk[j] = (unsigned int)f2b(v0) | ((unsigned int)f2b(v1) << 16);
    }
    unsigned int off = (unsigned int)(o*256 + d0*2) ^ (((unsigned int)(o & 7)) << 4);
    *(uint4*)((char*)out + off) = make_uint4(pk[0], pk[1], pk[2], pk[3]);
  }
}

// ---------------- big edge GEMM: msg = sum_h h1[e,h]*(xs@W2_h)  (+b2 block), scatter-add ---
// M=128 edges, 512 thr / 8 waves x 16 cols, 2-way h-parity, contiguous scatter.
// Inner loop: BARRIER-FREE per-wave async pipeline. Each wave stages ONLY its own 4KB
// o-strip of the next W2 block into LDS via global_load_lds (double-buffered; buffer B
// reuses the dead sX gather region), then drains with a per-wave s_waitcnt vmcnt(0)
// whose only outstanding op is that staging -- issued one full MFMA phase (~1240 cyc)
// earlier, so exposed latency ~= 0. vmcnt(0) (not counted N) is spill-proof (r8 lesson).
// sched_barrier(0) pins [wait][ds_reads][stage][MFMA] order (rule #18).
__global__ __launch_bounds__(512,1) void k_big(const unsigned short* __restrict__ outcur,
                                               const unsigned short* __restrict__ W2T,
                                               const float* __restrict__ h1T,
                                               const int* __restrict__ eidx,
                                               float* __restrict__ agg){
  __shared__ __align__(16) char lds[3*32768];
  char* wbufA = lds;                 // W2 block buffer A
  char* wbufB = lds + 32768;         // W2 block buffer B; doubles as the sX gather region
  float* sH   = (float*)(lds + 65536);   // 64 h-rows x 128 edges, f32
  int t = threadIdx.x, l = t & 63, w = t >> 6;
  int tile = blockIdx.x >> 1, par = blockIdx.x & 1;
  int e0 = tile * 128;
  int colc = w*16 + (l & 15);                       // this wave's 16 output cols
  unsigned lq16 = (unsigned)((l >> 4) * 16);
  unsigned swzc = ((unsigned)(colc & 7)) << 4;
  unsigned bofs0 = (unsigned)(colc*256 +   0 + lq16) ^ swzc;
  unsigned bofs1 = (unsigned)(colc*256 +  64 + lq16) ^ swzc;
  unsigned bofs2 = (unsigned)(colc*256 + 128 + lq16) ^ swzc;
  unsigned bofs3 = (unsigned)(colc*256 + 192 + lq16) ^ swzc;
  const char* gsrc = (const char*)W2T + w*4096 + l*16;   // per-lane src base (strip w)

#define KB_STAGE(LB, H) {                                                      \
    const char* g_ = gsrc + (size_t)(H)*32768;                                 \
    char* l_ = (LB) + w*4096;          /* wave-uniform LDS base; HW adds lane*16 */ \
    _Pragma("unroll")                                                          \
    for (int r_ = 0; r_ < 4; ++r_)                                             \
      __builtin_amdgcn_global_load_lds(                                        \
        (const __attribute__((address_space(1))) unsigned int*)(g_ + r_*1024), \
        (__attribute__((address_space(3))) unsigned int*)(l_ + r_*1024),       \
        16, 0, 0);                                                             \
  }

  KB_STAGE(wbufA, par);               // prologue: stage h=par, hidden under gather below
  { // gather 128 xs rows x 256B into wbufB (the sX region), XOR swizzle baked in
    int r = t >> 2, q = t & 3;
    int e = e0 + r;
    int srow = eidx[e < NE ? e : NE-1];
    const uint4* gp = (const uint4*)(outcur + (size_t)srow*128);
    #pragma unroll
    for (int i = 0; i < 4; ++i){
      uint4 v = gp[q*4 + i];
      unsigned off = (unsigned)((q*64 + i*16) ^ ((r & 7) << 4));
      *(uint4*)(wbufB + r*256 + off) = v;
    }
  }
  { // stage h1 slice: row hh -> h = par+2*hh, 128 f32 per row; nontemporal (read-once)
    #pragma unroll
    for (int i = 0; i < 4; ++i){
      int n = i*512 + t;
      int row = n >> 5, c4 = n & 31;
      const f32x4* src = ((const f32x4*)(h1T + (size_t)(par + 2*row)*EPAD + e0)) + c4;
      ((f32x4*)sH)[n] = __builtin_nontemporal_load(src);
    }
  }
  __syncthreads();                                  // sX + sH visible to all waves
  // A fragments: 128 rows persistent in registers for all h
  short8 af[8][4];
  #pragma unroll
  for (int mf = 0; mf < 8; ++mf){
    int row = mf*16 + (l & 15);
    #pragma unroll
    for (int kf = 0; kf < 4; ++kf){
      unsigned off = (unsigned)((kf*64 + ((l >> 4)*16)) ^ ((row & 7) << 4));
      af[mf][kf] = *(const short8*)(wbufB + row*256 + off);
    }
  }
  __syncthreads();                                  // all waves done with sX -> wbufB free
  f32x4 acc[8];
  #pragma unroll
  for (int mf = 0; mf < 8; ++mf) acc[mf] = (f32x4){0.f,0.f,0.f,0.f};
  const f32x4 zf = (f32x4){0.f,0.f,0.f,0.f};

#define KB_CHAIN(DST, MF)                                                            \
    DST = __builtin_amdgcn_mfma_f32_16x16x32_bf16(af[MF][0], bq0, zf,  0,0,0);       \
    DST = __builtin_amdgcn_mfma_f32_16x16x32_bf16(af[MF][1], bq1, DST, 0,0,0);       \
    DST = __builtin_amdgcn_mfma_f32_16x16x32_bf16(af[MF][2], bq2, DST, 0,0,0);       \
    DST = __builtin_amdgcn_mfma_f32_16x16x32_bf16(af[MF][3], bq3, DST, 0,0,0);

#define KB_FMA(MF, Y)                                                                \
    _Pragma("unroll")                                                                \
    for (int j_ = 0; j_ < 4; ++j_)                                                   \
      acc[MF][j_] = fmaf(hvv[MF][j_], Y[j_], acc[MF][j_]);

#define KB_ITER(CURB, NXTB, HH) {                                                    \
    asm volatile("s_waitcnt vmcnt(0)" ::: "memory");  /* CURB staging complete */    \
    __builtin_amdgcn_sched_barrier(0);                                               \
    short8 bq0 = *(const short8*)((CURB) + bofs0);                                   \
    short8 bq1 = *(const short8*)((CURB) + bofs1);                                   \
    short8 bq2 = *(const short8*)((CURB) + bofs2);                                   \
    short8 bq3 = *(const short8*)((CURB) + bofs3);                                   \
    f32x4 hvv[8];                                                                    \
    _Pragma("unroll")                                                                \
    for (int mf_ = 0; mf_ < 8; ++mf_)                                                \
      hvv[mf_] = *(const f32x4*)((const char*)sH + (HH)*512 + mf_*64 + lq16);        \
    __builtin_amdgcn_sched_barrier(0);       /* LDS reads stay above next stage */   \
    int hn_ = par + 2*((HH) + 1); if (hn_ > 128) hn_ = 128;                          \
    KB_STAGE(NXTB, hn_);                                                             \
    __builtin_amdgcn_sched_barrier(0);       /* stage issued before MFMA block */    \
    f32x4 Yc, Yp;                                                                    \
    __builtin_amdgcn_s_setprio(1);                                                   \
    KB_CHAIN(Yc, 0)                                                                  \
    Yp = Yc; KB_CHAIN(Yc, 1) KB_FMA(0, Yp)                                           \
    Yp = Yc; KB_CHAIN(Yc, 2) KB_FMA(1, Yp)                                           \
    Yp = Yc; KB_CHAIN(Yc, 3) KB_FMA(2, Yp)                                           \
    Yp = Yc; KB_CHAIN(Yc, 4) KB_FMA(3, Yp)                                           \
    Yp = Yc; KB_CHAIN(Yc, 5) KB_FMA(4, Yp)                                           \
    Yp = Yc; KB_CHAIN(Yc, 6) KB_FMA(5, Yp)                                           \
    Yp = Yc; KB_CHAIN(Yc, 7) KB_FMA(6, Yp)                                           \
    __builtin_amdgcn_s_setprio(0);                                                   \
    KB_FMA(7, Yc)                                                                    \
  }

  for (int hh = 0; hh < 64; hh += 2){
    KB_ITER(wbufA, wbufB, hh)          // compute h=par+2hh,   stage h=par+2hh+2 -> B
    KB_ITER(wbufB, wbufA, hh+1)        // compute h=par+2hh+2? no: h=par+2(hh+1), stage -> A
  }
  if (par == 0){
    // b2 block (h=128): staged into wbufA at hh=63; coeff 1 on valid rows
    asm volatile("s_waitcnt vmcnt(0)" ::: "memory");
    __builtin_amdgcn_sched_barrier(0);
    short8 bq0 = *(const short8*)(wbufA + bofs0);
    short8 bq1 = *(const short8*)(wbufA + bofs1);
    short8 bq2 = *(const short8*)(wbufA + bofs2);
    short8 bq3 = *(const short8*)(wbufA + bofs3);
    #pragma unroll
    for (int mf = 0; mf < 8; ++mf){
      f32x4 Y;
      KB_CHAIN(Y, mf)
      int rb = e0 + mf*16 + ((l >> 4) << 2);
      #pragma unroll
      for (int j = 0; j < 4; ++j)
        if (rb + j < NE) acc[mf][j] += Y[j];
    }
  }
#undef KB_ITER
#undef KB_FMA
#undef KB_CHAIN
#undef KB_STAGE
  // fused segment_sum: atomic scatter to agg[dst] (contiguous 64B per edge per wave)
  #pragma unroll
  for (int mf = 0; mf < 8; ++mf){
    #pragma unroll
    for (int j = 0; j < 4; ++j){
      int e = e0 + mf*16 + ((l >> 4) << 2) + j;
      int dst = (e < NE) ? eidx[NE + e] : 0;        // pad rows add 0.0
      atomicAdd(agg + (size_t)dst*128 + colc, acc[mf][j]);
    }
  }
}

// ---------------- small GEMM: C = act( Aa@Wa [+ Ab@Wb] [+ addin] + bias ) ----------------
// clr: if non-null, zero each addin element after reading it (folds next step's memset).
__global__ __launch_bounds__(256,2) void k_gsm(const unsigned short* __restrict__ Aa,
                                               const unsigned short* __restrict__ Wa,
                                               const unsigned short* __restrict__ Ab,
                                               const unsigned short* __restrict__ Wb,
                                               const float* __restrict__ addin,
                                               float* __restrict__ clr,
                                               const float* __restrict__ bias,
                                               int do_relu,
                                               unsigned short* __restrict__ outb,
                                               float* __restrict__ outf){
  __shared__ __align__(16) unsigned short sA[64*128];
  __shared__ __align__(16) unsigned short sW[128*128];
  int t = threadIdx.x, l = t & 63, w = t >> 6;
  int r0 = blockIdx.x * 64;
  f32x4 acc[4][2];
  #pragma unroll
  for (int mf = 0; mf < 4; ++mf)
    #pragma unroll
    for (int nf = 0; nf < 2; ++nf)
      acc[mf][nf] = (f32x4){0.f,0.f,0.f,0.f};
  const unsigned short* A = Aa;
  const unsigned short* W = Wa;
  for (int pass = 0; pass < 2; ++pass){
    if (pass == 1){
      if (Ab == nullptr) break;
      A = Ab; W = Wb;
      __syncthreads();                            // pass0 done with sA/sW
    }
    {
      const uint4* gp = (const uint4*)((const char*)A + (size_t)r0*256);
      uint4* lp = (uint4*)sA;
      #pragma unroll
      for (int i = 0; i < 4; ++i) lp[i*256 + t] = gp[i*256 + t];
      const uint4* gw = (const uint4*)W;
      uint4* lw = (uint4*)sW;
      #pragma unroll
      for (int i = 0; i < 8; ++i) lw[i*256 + t] = gw[i*256 + t];
    }
    __syncthreads();
    short8 af[4][4];
    #pragma unroll
    for (int mf = 0; mf < 4; ++mf)
      #pragma unroll
      for (int kf = 0; kf < 4; ++kf)
        af[mf][kf] = *(const short8*)((const char*)sA + (mf*16 + (l & 15))*256 + kf*64 + ((l >> 4)*16));
    #pragma unroll
    for (int nf = 0; nf < 2; ++nf){
      int col = w*32 + nf*16 + (l & 15);
      unsigned int swz = ((unsigned int)(col & 7)) << 4;
      #pragma unroll
      for (int kf = 0; kf < 4; ++kf){
        short8 bfr = *(const short8*)((const char*)sW +
                        (((unsigned int)(col*256 + kf*64 + ((l >> 4)*16))) ^ swz));
        #pragma unroll
        for (int mf = 0; mf < 4; ++mf)
          acc[mf][nf] = __builtin_amdgcn_mfma_f32_16x16x32_bf16(af[mf][kf], bfr, acc[mf][nf], 0, 0, 0);
      }
    }
  }
  #pragma unroll
  for (int mf = 0; mf < 4; ++mf){
    #pragma unroll
    for (int nf = 0; nf < 2; ++nf){
      #pragma unroll
      for (int j = 0; j < 4; ++j){
        int r = r0 + mf*16 + ((l >> 4) << 2) + j;
        int c = w*32 + nf*16 + (l & 15);
        float v = acc[mf][nf][j];
        if (addin) v += addin[(size_t)r*128 + c];
        if (clr)   clr[(size_t)r*128 + c] = 0.f;   // fold next k_big's memset
        v += bias[c];
        if (do_relu) v = fmaxf(v, 0.f);
        if (outb) outb[(size_t)r*128 + c] = f2b(v);
        if (outf) outf[(size_t)r*128 + c] = v;
      }
    }
  }
}

extern "C" void kernel_launch(void* const* d_in, const int* in_sizes, int n_in,
                              void* d_out, int out_size, void* d_ws, size_t ws_size,
                              hipStream_t stream){
  (void)in_sizes; (void)n_in; (void)out_size; (void)ws_size;
  const float* x    = (const float*)d_in[0];
  const float* ea   = (const float*)d_in[1];
  const float* W0   = (const float*)d_in[2];
  const float* b0   = (const float*)d_in[3];
  const float* W1   = (const float*)d_in[4];
  const float* b1   = (const float*)d_in[5];
  const float* W2   = (const float*)d_in[6];
  const float* b2   = (const float*)d_in[7];
  const float* root = (const float*)d_in[8];
  const float* bias = (const float*)d_in[9];
  const float* Wm   = (const float*)d_in[10];
  const float* bm   = (const float*)d_in[11];
  const int*   eidx = (const int*)d_in[12];

  char* p = (char*)d_ws;
  unsigned short* W2T = (unsigned short*)p; p += (size_t)129*32768;   // 4.23 MB (swizzled bf16)
  unsigned short* sWt = (unsigned short*)p; p += (size_t)4*32768;     // W0T,rootT,WmAT,WmBT
  float*          h1T = (float*)p;          p += (size_t)128*EPAD*4;  // 7.73 MB
  unsigned short* xb  = (unsigned short*)p; p += (size_t)NVX*128*2;
  unsigned short* oA  = (unsigned short*)p; p += (size_t)NVX*128*2;
  unsigned short* oB  = (unsigned short*)p; p += (size_t)NVX*128*2;
  unsigned short* mB  = (unsigned short*)p; p += (size_t)NVX*128*2;
  float*          agg = (float*)p;          p += (size_t)NVX*128*4;   // total ~24.4 MB

  k_cvt<<<1000, 256, 0, stream>>>(x, xb, NVX*128);
  k_h1 <<<EPAD/64, 256, 0, stream>>>(ea, W1, b1, h1T);
  k_wt <<<133,  256, 0, stream>>>(W2, b2, W0, root, Wm, W2T, sWt);
  // lin0: out = relu(x @ W0 + b0)
  k_gsm<<<125, 256, 0, stream>>>(xb, sWt + 0*16384,
                                 (const unsigned short*)nullptr, (const unsigned short*)nullptr,
                                 (const float*)nullptr, (float*)nullptr, b0, 1, oA, (float*)nullptr);
  unsigned short* cur = oA;
  unsigned short* nxt = oB;
  for (int s = 0; s < 3; ++s){
    if (s == 0) hipMemsetAsync(agg, 0, (size_t)NVX*128*4, stream);  // steps 1,2 cleared by k_gsm
    k_big<<<2*NT_E, 512, 0, stream>>>(cur, W2T, h1T, eidx, agg);
    // m = relu(agg + out@root + bias); zero agg for the next step's atomics
    k_gsm<<<125, 256, 0, stream>>>(cur, sWt + 1*16384,
                                   (const unsigned short*)nullptr, (const unsigned short*)nullptr,
                                   agg, (s < 2) ? agg : (float*)nullptr, bias, 1, mB, (float*)nullptr);
    if (s < 2){
      // out_next = m@Wm[:128] + out@Wm[128:] + bm
      k_gsm<<<125, 256, 0, stream>>>(mB, sWt + 2*16384, cur, sWt + 3*16384,
                                     (const float*)nullptr, (float*)nullptr, bm, 0, nxt, (float*)nullptr);
    } else {
      // final: d_out = m@Wm[:128] + out@Wm[128:] + bm + x
      k_gsm<<<125, 256, 0, stream>>>(mB, sWt + 2*16384, cur, sWt + 3*16384,
                                     x, (float*)nullptr, bm, 0, (unsigned short*)nullptr, (float*)d_out);
    }
    unsigned short* tsw = cur; cur = nxt; nxt = tsw;
  }
}